// Round 1
// baseline (1783.368 us; speedup 1.0000x reference)
//
#include <hip/hip_runtime.h>

// RNN: B=512, T=1024, I=64, H=128, fp32.
// Fused persistent kernel: 256 blocks x 256 threads; block handles 2 batch
// rows; thread = (row r, hidden j). Weights register-resident (192 VGPRs),
// h double-buffered in LDS (broadcast reads), x chunk-prefetched into LDS.

#define Bsz 512
#define Tt  1024
#define Ii  64
#define Hh  128
constexpr int ROWS = 2;       // batch rows per block
constexpr int TC   = 16;      // timesteps staged per LDS chunk
constexpr int NTHREADS = 256;

__device__ __forceinline__ float fast_tanh(float x) {
    // tanh(x) = 1 - 2/(exp2(2*log2(e)*x) + 1); exact limits at +-inf
    float t = __builtin_amdgcn_exp2f(x * 2.8853900817779268f);
    return 1.0f - 2.0f * __builtin_amdgcn_rcpf(t + 1.0f);
}

__device__ __forceinline__ float fast_sigmoid(float z) {
    float t = __builtin_amdgcn_exp2f(-z * 1.4426950408889634f);
    return __builtin_amdgcn_rcpf(1.0f + t);
}

__global__ __launch_bounds__(NTHREADS)
void rnn_fused(const float* __restrict__ x,
               const float* __restrict__ W_ih,
               const float* __restrict__ W_hh,
               const float* __restrict__ b_ih,
               const float* __restrict__ b_hh,
               const float* __restrict__ fc_w,
               const float* __restrict__ fc_b,
               float* __restrict__ out)
{
    __shared__ float xs[2][ROWS * TC * Ii];   // 2 x 8 KB, double-buffered x chunks
    __shared__ float hbuf[2][ROWS][Hh];       // 2 KB, double-buffered hidden state
    __shared__ float wred[4];                 // per-wave partials for epilogue

    const int tid = threadIdx.x;
    const int r   = tid >> 7;        // 0..1  batch row within block
    const int j   = tid & (Hh - 1);  // 0..127 hidden unit
    const int bb  = blockIdx.x * ROWS;

    // ---- weights into registers (one-time; L2-served after first blocks) ----
    float4 wih[Ii / 4];   // W_ih[j][0..63]
    float4 whh[Hh / 4];   // W_hh[j][0..127]
    {
        const float4* g = (const float4*)(W_ih + j * Ii);
        #pragma unroll
        for (int k = 0; k < Ii / 4; ++k) wih[k] = g[k];
    }
    {
        const float4* g = (const float4*)(W_hh + j * Hh);
        #pragma unroll
        for (int k = 0; k < Hh / 4; ++k) whh[k] = g[k];
    }
    const float bias = b_ih[j] + b_hh[j];

    hbuf[0][r][j] = 0.0f;   // h0 = 0 (256 threads cover [2][128] exactly)

    // ---- x chunk prefetch: 2 float4 per thread per chunk (contiguous 4KB/row) ----
    const int f0 = tid, f1 = tid + NTHREADS;
    auto src = [&](int t0, int f) {
        int rr  = f >> 8;        // row within block
        int off = f & 255;       // float4 offset inside the row's 16x64 chunk
        return ((const float4*)(x + ((size_t)(bb + rr) * Tt + t0) * Ii))[off];
    };

    float4 p0 = src(0, f0);
    float4 p1 = src(0, f1);

    int   cur   = 0;
    int   cbuf  = 1;
    float hlast = 0.0f;

    for (int t0 = 0; t0 < Tt; t0 += TC) {
        cbuf ^= 1;
        ((float4*)xs[cbuf])[f0] = p0;      // store staged chunk (waitcnt auto)
        ((float4*)xs[cbuf])[f1] = p1;
        if (t0 + TC < Tt) {                // prefetch next chunk; lands during compute
            p0 = src(t0 + TC, f0);
            p1 = src(t0 + TC, f1);
        }
        __syncthreads();                   // chunk + h-init/writes visible

        #pragma unroll 1
        for (int tt = 0; tt < TC; ++tt) {
            const float4* xv = (const float4*)(xs[cbuf] + (r * TC + tt) * Ii);
            const float4* hv = (const float4*)(hbuf[cur][r]);

            float a0 = 0.f, a1 = 0.f, a2 = 0.f, a3 = 0.f;
            #pragma unroll
            for (int k = 0; k < Ii / 4; ++k) {   // input projection: 64 MAC
                float4 xx = xv[k]; float4 w = wih[k];
                a0 += xx.x * w.x; a1 += xx.y * w.y;
                a2 += xx.z * w.z; a3 += xx.w * w.w;
            }
            #pragma unroll
            for (int k = 0; k < Hh / 4; ++k) {   // recurrence: 128 MAC
                float4 hh = hv[k]; float4 w = whh[k];
                a0 += hh.x * w.x; a1 += hh.y * w.y;
                a2 += hh.z * w.z; a3 += hh.w * w.w;
            }
            float z = bias + ((a0 + a1) + (a2 + a3));
            hlast = fast_tanh(z);
            hbuf[cur ^ 1][r][j] = hlast;
            __syncthreads();               // double-buffer: 1 barrier/step
            cur ^= 1;
        }
    }

    // ---- epilogue: out[b] = sigmoid(fc_b + sum_j fc_w[j] * h[b][j]) ----
    float partial = fc_w[j] * hlast;
    #pragma unroll
    for (int off = 32; off > 0; off >>= 1)
        partial += __shfl_down(partial, off, 64);
    if ((tid & 63) == 0) wred[tid >> 6] = partial;
    __syncthreads();
    if ((tid & 127) == 0) {
        int w0 = tid >> 6;                 // 0 (r=0) or 2 (r=1)
        float zz = fc_b[0] + wred[w0] + wred[w0 + 1];
        out[bb + r] = fast_sigmoid(zz);
    }
}

extern "C" void kernel_launch(void* const* d_in, const int* in_sizes, int n_in,
                              void* d_out, int out_size, void* d_ws, size_t ws_size,
                              hipStream_t stream) {
    const float* x    = (const float*)d_in[0];
    const float* W_ih = (const float*)d_in[1];
    const float* W_hh = (const float*)d_in[2];
    const float* b_ih = (const float*)d_in[3];
    const float* b_hh = (const float*)d_in[4];
    const float* fc_w = (const float*)d_in[5];
    const float* fc_b = (const float*)d_in[6];
    float* out = (float*)d_out;

    rnn_fused<<<Bsz / ROWS, NTHREADS, 0, stream>>>(
        x, W_ih, W_hh, b_ih, b_hh, fc_w, fc_b, out);
}

// Round 2
// 700.748 us; speedup vs baseline: 2.5450x; 2.5450x over previous
//
#include <hip/hip_runtime.h>

// RNN: B=512, T=1024, I=64, H=128, fp32. Latency-bound recurrence.
// K-split-4 persistent kernel: 512 blocks (1 batch row each) x 512 threads.
// thread = (j = tid>>2, kq = tid&3): computes a K-quarter of h_next[j]'s dot
// product (16 of I=64, 32 of H=128), quad-shuffle reduce, all lanes tanh.
// Weights: 48 floats/thread in VGPRs (fits 128-reg budget -> no spill).
// h double-buffered in LDS; h reads rotation-swizzled to avoid 4-way bank
// conflicts between the kq address streams. x chunk-prefetched into LDS.

#define Bsz 512
#define Tt  1024
#define Ii  64
#define Hh  128
constexpr int TC = 32;          // timesteps staged per LDS chunk
constexpr int NT = 512;         // threads per block (8 waves)

__device__ __forceinline__ float fast_tanh(float x) {
    // tanh(x) = 1 - 2/(exp2(2*log2(e)*x) + 1); exact limits at +-inf
    float t = __builtin_amdgcn_exp2f(x * 2.8853900817779268f);
    return 1.0f - 2.0f * __builtin_amdgcn_rcpf(t + 1.0f);
}

__device__ __forceinline__ float fast_sigmoid(float z) {
    float t = __builtin_amdgcn_exp2f(-z * 1.4426950408889634f);
    return __builtin_amdgcn_rcpf(1.0f + t);
}

__global__ __launch_bounds__(NT, 4)   // cap at 128 VGPR: 4 waves/EU
void rnn_fused(const float* __restrict__ x,
               const float* __restrict__ W_ih,
               const float* __restrict__ W_hh,
               const float* __restrict__ b_ih,
               const float* __restrict__ b_hh,
               const float* __restrict__ fc_w,
               const float* __restrict__ fc_b,
               float* __restrict__ out)
{
    __shared__ float xs[2][TC * Ii];   // 2 x 8 KB double-buffered x chunks
    __shared__ float hbuf[2][Hh];      // 1 KB double-buffered hidden state
    __shared__ float wred[NT / 64];

    const int tid = threadIdx.x;
    const int j   = tid >> 2;          // 0..127 hidden unit
    const int kq  = tid & 3;           // K-quarter
    const int row = blockIdx.x;        // batch row
    const int rot = (2 * kq) & 7;      // bank-conflict-avoiding rotation

    // ---- weights into registers (48 floats = 12 float4) ----
    float4 wih[4];                     // W_ih[j][16*kq .. +16)
    {
        const float4* g = (const float4*)(W_ih + j * Ii + kq * 16);
        #pragma unroll
        for (int k = 0; k < 4; ++k) wih[k] = g[k];
    }
    float4 whh[8];                     // W_hh[j][32*kq .. +32), rotation-permuted
    {
        const float4* g = (const float4*)(W_hh + j * Hh + kq * 32);
        #pragma unroll
        for (int i = 0; i < 8; ++i) whh[i] = g[(i + rot) & 7];
    }
    const float bias = b_ih[j] + b_hh[j];

    if (kq == 0) hbuf[0][j] = 0.0f;    // h0 = 0

    // ---- x chunk prefetch: 1 float4/thread/chunk (8 KB contiguous) ----
    const float4* xsrc = (const float4*)(x + (size_t)row * Tt * Ii);
    float4 pf = xsrc[tid];             // chunk 0 (TC*Ii/4 = 512 float4 = NT)

    int   cur   = 0;
    float hlast = 0.0f;

    for (int t0 = 0; t0 < Tt; t0 += TC) {
        const int cbuf = (t0 / TC) & 1;
        ((float4*)xs[cbuf])[tid] = pf;
        if (t0 + TC < Tt) pf = xsrc[(t0 + TC) * (Ii / 4) + tid];
        __syncthreads();               // chunk + h writes visible

        #pragma unroll 1
        for (int tt = 0; tt < TC; ++tt) {
            const float4* xv = (const float4*)(xs[cbuf] + tt * Ii) + kq * 4;
            const float4* hv = (const float4*)(hbuf[cur]) + kq * 8;

            float a0 = 0.f, a1 = 0.f, a2 = 0.f, a3 = 0.f;
            #pragma unroll
            for (int k = 0; k < 4; ++k) {          // input proj quarter: 16 MAC
                float4 xx = xv[k]; float4 w = wih[k];
                a0 += xx.x * w.x; a1 += xx.y * w.y;
                a2 += xx.z * w.z; a3 += xx.w * w.w;
            }
            #pragma unroll
            for (int i = 0; i < 8; ++i) {          // recurrence quarter: 32 MAC
                float4 hh = hv[(i + rot) & 7];     // swizzled: kq streams on
                float4 w  = whh[i];                // disjoint banks
                a0 += hh.x * w.x; a1 += hh.y * w.y;
                a2 += hh.z * w.z; a3 += hh.w * w.w;
            }
            float p = (a0 + a1) + (a2 + a3);
            p += __shfl_xor(p, 1, 64);             // quad reduce
            p += __shfl_xor(p, 2, 64);
            float z = p + bias;
            hlast = fast_tanh(z);
            if (kq == 0) hbuf[cur ^ 1][j] = hlast;
            __syncthreads();           // h_next visible to all waves
            cur ^= 1;
        }
    }

    // ---- epilogue: out[row] = sigmoid(fc_b + sum_j fc_w[j] * h[j]) ----
    float partial = (kq == 0) ? fc_w[j] * hlast : 0.0f;
    #pragma unroll
    for (int off = 32; off > 0; off >>= 1)
        partial += __shfl_down(partial, off, 64);
    if ((tid & 63) == 0) wred[tid >> 6] = partial;
    __syncthreads();
    if (tid == 0) {
        float zz = fc_b[0];
        #pragma unroll
        for (int w = 0; w < NT / 64; ++w) zz += wred[w];
        out[row] = fast_sigmoid(zz);
    }
}

extern "C" void kernel_launch(void* const* d_in, const int* in_sizes, int n_in,
                              void* d_out, int out_size, void* d_ws, size_t ws_size,
                              hipStream_t stream) {
    const float* x    = (const float*)d_in[0];
    const float* W_ih = (const float*)d_in[1];
    const float* W_hh = (const float*)d_in[2];
    const float* b_ih = (const float*)d_in[3];
    const float* b_hh = (const float*)d_in[4];
    const float* fc_w = (const float*)d_in[5];
    const float* fc_b = (const float*)d_in[6];
    float* out = (float*)d_out;

    rnn_fused<<<Bsz, NT, 0, stream>>>(x, W_ih, W_hh, b_ih, b_hh, fc_w, fc_b, out);
}